// Round 10
// baseline (194.906 us; speedup 1.0000x reference)
//
#include <hip/hip_runtime.h>
#include <hip/hip_bf16.h>
#include <math.h>

typedef unsigned long long u64;
typedef unsigned int u32;
typedef __hip_bfloat16 bf16;

#define N 1024
#define NCLS 21
#define APP 1024
#define DF 128
#define NH 16
#define DK 64
#define NS 4     // n-splits in flash attention

typedef __attribute__((ext_vector_type(8))) short short8v;
typedef __attribute__((ext_vector_type(4))) float float4v;
union U4S8 { uint4 u; short8v s; };

__device__ __forceinline__ float b2f(bf16 x) { return __bfloat162float(x); }
__device__ __forceinline__ ushort f2bu(float x) { bf16 b = __float2bfloat16(x); return *(ushort*)&b; }
__device__ __forceinline__ float bu2f(ushort u) { return __uint_as_float(((uint)u) << 16); }

// ---------------------------------------------------------------- k_prepsort
// One block, 1024 threads: softmax/argmax/bbox-decode + rank-by-count sort.
__global__ void __launch_bounds__(1024) k_prepsort(
        const float* __restrict__ roi, const float* __restrict__ cls_loc,
        const float* __restrict__ score, const int* __restrict__ size,
        int* __restrict__ order, float* __restrict__ sprob,
        float* __restrict__ sbbox, float* __restrict__ out)
{
    __shared__ u64 sk[N];
    int i = threadIdx.x;
    float s[NCLS];
    float mx = -1e30f; int am = 0;
    for (int c = 0; c < NCLS; c++) {
        s[c] = score[i * NCLS + c];
        if (s[c] > mx) { mx = s[c]; am = c; }
    }
    float sum = 0.f;
    for (int c = 0; c < NCLS; c++) sum += expf(s[c] - mx);
    float p = 1.0f / sum;

    float y0 = roi[i*4+0], x0 = roi[i*4+1];
    float y1 = roi[i*4+2], x1 = roi[i*4+3];
    float hh = y1 - y0, ww = x1 - x0;
    float cy = y0 + 0.5f * hh, cx = x0 + 0.5f * ww;
    float l0 = cls_loc[i*84 + am*4 + 0] * 0.1f;
    float l1 = cls_loc[i*84 + am*4 + 1] * 0.1f;
    float l2 = cls_loc[i*84 + am*4 + 2] * 0.2f;
    float l3 = cls_loc[i*84 + am*4 + 3] * 0.2f;
    float ncy = l0 * hh + cy, ncx = l1 * ww + cx;
    float nh = expf(l2) * hh, nw = expf(l3) * ww;
    float b0 = ncy - 0.5f * nh, b1 = ncx - 0.5f * nw;
    float b2v = ncy + 0.5f * nh, b3 = ncx + 0.5f * nw;
    float lim = ((am & 1) == 0) ? (float)size[0] : (float)size[1];
    b0  = fminf(fmaxf(b0, 0.f), lim);
    b1  = fminf(fmaxf(b1, 0.f), lim);
    b2v = fminf(fmaxf(b2v, 0.f), lim);
    b3  = fminf(fmaxf(b3, 0.f), lim);

    u64 my = ((u64)(0xFFFFFFFFu - __float_as_uint(p)) << 32) | (u32)i;
    sk[i] = my;
    __syncthreads();
    int r = 0;
    for (int j = 0; j < N; j++) r += (sk[j] < my) ? 1 : 0;
    order[r] = i;
    sprob[r] = p;
    sbbox[r*4+0] = b0; sbbox[r*4+1] = b1; sbbox[r*4+2] = b2v; sbbox[r*4+3] = b3;
    out[N + r] = (float)(am - 1);
    out[2*N + r*4 + 0] = b0;
    out[2*N + r*4 + 1] = b1;
    out[2*N + r*4 + 2] = b2v;
    out[2*N + r*4 + 3] = b3;
}

// ---------------------------------------------------------------- k_emb4 (MFMA, 8 partials)
// part[ph*4+dg][row][col]; each block loops 4 d-chunks, accumulating in regs.
__global__ void __launch_bounds__(256) k_emb4(
        const int* __restrict__ order, const float* __restrict__ app,
        const float* __restrict__ feat_w, const float* __restrict__ rank_w,
        float* __restrict__ part)
{
    __shared__ ushort sA[64][72];
    __shared__ ushort sW[128][72];
    __shared__ int sOrd[64];
    int rt = blockIdx.x, dg = blockIdx.y, ph = blockIdx.z, t = threadIdx.x;
    int r0 = rt * 64;
    int w = t >> 6, l = t & 63, l15 = l & 15, quad = l >> 4;
    if (t < 64) sOrd[t] = order[r0 + t];
    __syncthreads();

    const float* Wsrc = ph ? rank_w : feat_w;
    float4v acc[8];
    #pragma unroll
    for (int nb = 0; nb < 8; nb++) acc[nb] = (float4v){0.f, 0.f, 0.f, 0.f};

    for (int dc = dg * 4; dc < dg * 4 + 4; dc++) {
        int d0 = dc * 64;
        #pragma unroll
        for (int it = 0; it < 32; it++) {
            int idx = t + it * 256;
            int d = idx >> 7, c = idx & 127;
            sW[c][d] = f2bu(Wsrc[(size_t)(d0 + d) * 128 + c]);
        }
        if (ph == 0) {
            #pragma unroll
            for (int it = 0; it < 16; it++) {
                int idx = t + it * 256;
                int r = idx >> 6, d = idx & 63;
                sA[r][d] = f2bu(app[(size_t)sOrd[r] * 1024 + d0 + d]);
            }
        } else {
            #pragma unroll
            for (int it = 0; it < 16; it++) {
                int idx = t + it * 256;
                int r = idx >> 6, d = idx & 63;
                int dgl = d0 + d;
                float irow = (float)(r0 + r);
                float val;
                if (dgl < 512) val = __sinf(irow * exp2f(-(float)dgl * 0.019464422f));
                else           val = __cosf(irow * exp2f(-(float)(dgl - 512) * 0.019464422f));
                sA[r][d] = f2bu(val);
            }
        }
        __syncthreads();
        U4S8 Af0, Af1;
        Af0.u = *(uint4*)&sA[w*16 + l15][quad*8];
        Af1.u = *(uint4*)&sA[w*16 + l15][32 + quad*8];
        #pragma unroll
        for (int nb = 0; nb < 8; nb++) {
            U4S8 Bf0, Bf1;
            Bf0.u = *(uint4*)&sW[nb*16 + l15][quad*8];
            Bf1.u = *(uint4*)&sW[nb*16 + l15][32 + quad*8];
            acc[nb] = __builtin_amdgcn_mfma_f32_16x16x32_bf16(Af0.s, Bf0.s, acc[nb], 0, 0, 0);
            acc[nb] = __builtin_amdgcn_mfma_f32_16x16x32_bf16(Af1.s, Bf1.s, acc[nb], 0, 0, 0);
        }
        __syncthreads();
    }
    #pragma unroll
    for (int reg = 0; reg < 4; reg++) {
        int row = r0 + w*16 + quad*4 + reg;
        #pragma unroll
        for (int nb = 0; nb < 8; nb++)
            part[(((size_t)ph * 4 + dg) * 1024 + row) * 128 + nb*16 + l15] = acc[nb][reg];
    }
}

// ---------------------------------------------------------------- k_embsum (-> bf16)
__global__ void k_embsum(const float* __restrict__ part,
                         const float* __restrict__ feat_b, const float* __restrict__ rank_b,
                         bf16* __restrict__ embb)
{
    int gid = blockIdx.x * 256 + threadIdx.x;
    int c = gid & 127;
    float acc = feat_b[c] + rank_b[c];
    #pragma unroll
    for (int p8 = 0; p8 < 8; p8++) acc += part[(size_t)p8 * 131072 + gid];
    embb[gid] = __float2bfloat16(acc);
}

// ---------------------------------------------------------------- k_qkv2 (MFMA)
__global__ void __launch_bounds__(256) k_qkv2(
        const bf16* __restrict__ embb,
        const float* __restrict__ wq, const float* __restrict__ bq,
        const float* __restrict__ wk, const float* __restrict__ bk,
        const float* __restrict__ wv, const float* __restrict__ bv,
        bf16* __restrict__ q, bf16* __restrict__ k, bf16* __restrict__ v)
{
    __shared__ ushort sWt[64][136];
    int t = threadIdx.x;
    int rt = blockIdx.x, h = blockIdx.y, mat = blockIdx.z;
    const float* W  = (mat == 0) ? wq : (mat == 1) ? wk : wv;
    const float* Bb = (mat == 0) ? bq : (mat == 1) ? bk : bv;
    bf16* Out       = (mat == 0) ? q  : (mat == 1) ? k  : v;

    #pragma unroll
    for (int i = 0; i < 32; i++) {
        int idx = t + i * 256;
        int d = idx >> 6, kk = idx & 63;
        sWt[kk][d] = f2bu(W[((size_t)h * 128 + d) * 64 + kk]);
    }
    int w = t >> 6, l = t & 63, l15 = l & 15, quad = l >> 4;
    float biasv[4];
    #pragma unroll
    for (int nb = 0; nb < 4; nb++) biasv[nb] = Bb[h * 64 + nb*16 + l15];
    __syncthreads();

    U4S8 Bf[4][4];
    #pragma unroll
    for (int nb = 0; nb < 4; nb++)
        #pragma unroll
        for (int kc = 0; kc < 4; kc++)
            Bf[nb][kc].u = *(uint4*)&sWt[nb*16 + l15][kc*32 + quad*8];

    const uint4* A4 = (const uint4*)embb;
    int r0 = rt * 128 + w * 32;
    ushort* outu = (ushort*)Out;
    for (int mb = 0; mb < 2; mb++) {
        int arow = r0 + mb*16 + l15;
        U4S8 Af[4];
        #pragma unroll
        for (int kc = 0; kc < 4; kc++) Af[kc].u = A4[(size_t)arow * 16 + kc*4 + quad];
        float4v acc[4];
        #pragma unroll
        for (int nb = 0; nb < 4; nb++) acc[nb] = (float4v){0.f, 0.f, 0.f, 0.f};
        #pragma unroll
        for (int kc = 0; kc < 4; kc++)
            #pragma unroll
            for (int nb = 0; nb < 4; nb++)
                acc[nb] = __builtin_amdgcn_mfma_f32_16x16x32_bf16(Af[kc].s, Bf[nb][kc].s, acc[nb], 0, 0, 0);
        #pragma unroll
        for (int reg = 0; reg < 4; reg++) {
            int orow = r0 + mb*16 + quad*4 + reg;
            #pragma unroll
            for (int nb = 0; nb < 4; nb++)
                outu[((size_t)h * N + orow) * 64 + nb*16 + l15] = f2bu(acc[nb][reg] + biasv[nb]);
        }
    }
}

// ---------------------------------------------------------------- k_geo2 (MFMA head-projection)
__global__ void __launch_bounds__(256) k_geo2(
        const float* __restrict__ sbbox, const float* __restrict__ wgw,
        const float* __restrict__ wgb, bf16* __restrict__ lw)
{
    __shared__ ushort sE[256][72];
    __shared__ uint   sOut[NH][132];
    __shared__ float  mbb[4];
    int m = blockIdx.x, nc = blockIdx.y, t = threadIdx.x;
    int w = t >> 6, l = t & 63, l15 = l & 15, quad = l >> 4;

    if (t == 0) {
        float b0 = sbbox[m*4+0], b1 = sbbox[m*4+1], b2 = sbbox[m*4+2], b3 = sbbox[m*4+3];
        mbb[0] = (b0 + b2) * 0.5f; mbb[1] = (b1 + b3) * 0.5f;
        mbb[2] = b2 - b0 + 1.0f;   mbb[3] = b3 - b1 + 1.0f;
    }
    U4S8 Bg0, Bg1;
    #pragma unroll
    for (int j = 0; j < 8; j++) {
        ((ushort*)&Bg0)[j] = f2bu(wgw[l15*64 + quad*8 + j]);
        ((ushort*)&Bg1)[j] = f2bu(wgw[l15*64 + 32 + quad*8 + j]);
    }
    float bias = wgb[l15];
    __syncthreads();

    int n = nc * 256 + t;
    float b0 = sbbox[n*4+0], b1 = sbbox[n*4+1], b2 = sbbox[n*4+2], b3 = sbbox[n*4+3];
    float cxn = (b0 + b2) * 0.5f, cyn = (b1 + b3) * 0.5f;
    float wn = b2 - b0 + 1.0f, hn = b3 - b1 + 1.0f;
    float dx = __logf(fmaxf(fabsf((mbb[0] - cxn) / mbb[2]), 1e-3f));
    float dy = __logf(fmaxf(fabsf((mbb[1] - cyn) / mbb[3]), 1e-3f));
    float dw = __logf(mbb[2] / wn);
    float dh = __logf(mbb[3] / hn);
    float pos[4] = { dx, dy, dw, dh };
    const float dmt[8] = { 1.0f, 0.42169650342f, 0.177827941f, 0.0749894209f,
                           0.0316227766f, 0.01333521432f, 0.00562341325f, 0.00237137371f };
    float args[32];
    #pragma unroll
    for (int c = 0; c < 4; c++)
        #pragma unroll
        for (int f = 0; f < 8; f++) args[c*8 + f] = 100.0f * pos[c] * dmt[f];
    uint* rowp = (uint*)&sE[t][0];
    #pragma unroll
    for (int jj = 0; jj < 16; jj++) {
        float s0 = __sinf(args[2*jj]), s1 = __sinf(args[2*jj+1]);
        rowp[jj] = (uint)f2bu(s0) | ((uint)f2bu(s1) << 16);
    }
    #pragma unroll
    for (int jj = 0; jj < 16; jj++) {
        float c0 = __cosf(args[2*jj]), c1 = __cosf(args[2*jj+1]);
        rowp[16 + jj] = (uint)f2bu(c0) | ((uint)f2bu(c1) << 16);
    }
    __syncthreads();

    #pragma unroll
    for (int mt2 = 0; mt2 < 4; mt2++) {
        int prow = w*64 + mt2*16 + l15;
        U4S8 Af0, Af1;
        Af0.u = *(uint4*)&sE[prow][quad*8];
        Af1.u = *(uint4*)&sE[prow][32 + quad*8];
        float4v c = (float4v){0.f, 0.f, 0.f, 0.f};
        c = __builtin_amdgcn_mfma_f32_16x16x32_bf16(Af0.s, Bg0.s, c, 0, 0, 0);
        c = __builtin_amdgcn_mfma_f32_16x16x32_bf16(Af1.s, Bg1.s, c, 0, 0, 0);
        float v0 = __logf(fmaxf(fmaxf(c[0] + bias, 0.f), 1e-6f));
        float v1 = __logf(fmaxf(fmaxf(c[1] + bias, 0.f), 1e-6f));
        float v2 = __logf(fmaxf(fmaxf(c[2] + bias, 0.f), 1e-6f));
        float v3 = __logf(fmaxf(fmaxf(c[3] + bias, 0.f), 1e-6f));
        int pb = (w*64 + mt2*16 + quad*4) >> 1;
        sOut[l15][pb]     = (uint)f2bu(v0) | ((uint)f2bu(v1) << 16);
        sOut[l15][pb + 1] = (uint)f2bu(v2) | ((uint)f2bu(v3) << 16);
    }
    __syncthreads();
    uint* lwu = (uint*)lw;
    #pragma unroll
    for (int it = 0; it < 8; it++) {
        int idx = t + it * 256;
        int hh = idx >> 7, col = idx & 127;
        lwu[((size_t)hh << 19) + ((size_t)m << 9) + nc*128 + col] = sOut[hh][col];
    }
}

// ---------------------------------------------------------------- k_attn4 (MFMA flash, n-split)
__global__ void __launch_bounds__(256) k_attn4(
        const bf16* __restrict__ q, const bf16* __restrict__ kmat,
        const bf16* __restrict__ v, const bf16* __restrict__ lw,
        bf16* __restrict__ opartb, float* __restrict__ mpart, float* __restrict__ zpart)
{
    __shared__ uint sQu[64][36];
    __shared__ uint sVtu[64][36];
    __shared__ uint slwu[64][36];
    __shared__ uint sPu[4][16][36];

    int t = threadIdx.x;
    int mt = blockIdx.x, h = blockIdx.y, ns = blockIdx.z;
    int m0 = mt * 64;
    int w = t >> 6, l = t & 63, l15 = l & 15, quad = l >> 4;

    U4S8 kf0, kf1;
    {
        const uint4* k4 = (const uint4*)kmat;
        size_t krow = ((size_t)h * N + m0 + w*16 + l15) * 8;
        kf0.u = k4[krow + quad];
        kf1.u = k4[krow + 4 + quad];
    }

    float4v O[4];
    float M[4], Z[4];
    #pragma unroll
    for (int i = 0; i < 4; i++) {
        O[i] = (float4v){0.f, 0.f, 0.f, 0.f};
        M[i] = -1e30f; Z[i] = 0.f;
    }

    const uint* qsrc = (const uint*)q;
    const uint* vsrc = (const uint*)v;
    const uint* lwsrc = (const uint*)lw;

    for (int tile = ns * (16/NS); tile < (ns + 1) * (16/NS); tile++) {
        int n0 = tile * 64;
        #pragma unroll
        for (int i = 0; i < 8; i++) {
            int idx = t + i * 256;
            int nj = idx >> 5, kp = idx & 31;
            sQu[nj][kp] = qsrc[((size_t)h * N + n0 + nj) * 32 + kp];
        }
        #pragma unroll
        for (int i = 0; i < 4; i++) {
            int idx = t + i * 256;
            int a = idx & 31, nh2 = idx >> 5;
            uint g0 = vsrc[((size_t)h * N + n0 + 2*nh2) * 32 + a];
            uint g1 = vsrc[((size_t)h * N + n0 + 2*nh2 + 1) * 32 + a];
            sVtu[2*a][nh2]     = (g0 & 0xFFFFu) | (g1 << 16);
            sVtu[2*a + 1][nh2] = (g0 >> 16) | (g1 & 0xFFFF0000u);
        }
        #pragma unroll
        for (int i = 0; i < 8; i++) {
            int idx = t + i * 256;
            int mi = idx >> 5, np = idx & 31;
            slwu[mi][np] = lwsrc[((size_t)h << 19) + ((size_t)(m0 + mi) << 9) + (n0 >> 1) + np];
        }
        __syncthreads();

        float4v S[4];
        #pragma unroll
        for (int nb = 0; nb < 4; nb++) {
            U4S8 bq0, bq1;
            bq0.u = *(uint4*)&sQu[nb*16 + l15][quad*4];
            bq1.u = *(uint4*)&sQu[nb*16 + l15][16 + quad*4];
            float4v zz = (float4v){0.f, 0.f, 0.f, 0.f};
            float4v p0 = __builtin_amdgcn_mfma_f32_16x16x32_bf16(kf0.s, bq0.s, zz, 0, 0, 0);
            S[nb] = __builtin_amdgcn_mfma_f32_16x16x32_bf16(kf1.s, bq1.s, p0, 0, 0, 0);
        }
        ushort* pRow[4];
        #pragma unroll
        for (int r = 0; r < 4; r++) pRow[r] = (ushort*)&sPu[w][quad*4 + r][0];
        #pragma unroll
        for (int r = 0; r < 4; r++) {
            int mi = w*16 + quad*4 + r;
            float sv[4];
            #pragma unroll
            for (int nb = 0; nb < 4; nb++) {
                int col = nb*16 + l15;
                uint lu = slwu[mi][col >> 1];
                float lv = (col & 1) ? __uint_as_float(lu & 0xFFFF0000u)
                                     : __uint_as_float(lu << 16);
                sv[nb] = S[nb][r] * 0.125f + lv;
            }
            float rm = fmaxf(fmaxf(sv[0], sv[1]), fmaxf(sv[2], sv[3]));
            #pragma unroll
            for (int off = 1; off < 16; off <<= 1)
                rm = fmaxf(rm, __shfl_xor(rm, off, 64));
            float newM = fmaxf(M[r], rm);
            float pr[4], rs = 0.f;
            #pragma unroll
            for (int nb = 0; nb < 4; nb++) {
                pr[nb] = __expf(sv[nb] - newM);
                rs += pr[nb];
            }
            #pragma unroll
            for (int off = 1; off < 16; off <<= 1)
                rs += __shfl_xor(rs, off, 64);
            float sc = __expf(M[r] - newM);
            M[r] = newM;
            Z[r] = Z[r] * sc + rs;
            #pragma unroll
            for (int kvb = 0; kvb < 4; kvb++) O[kvb][r] *= sc;
            #pragma unroll
            for (int nb = 0; nb < 4; nb++)
                pRow[r][nb*16 + l15] = f2bu(pr[nb]);
        }
        {
            U4S8 ap0, ap1;
            ap0.u = *(uint4*)&sPu[w][l15][quad*4];
            ap1.u = *(uint4*)&sPu[w][l15][16 + quad*4];
            #pragma unroll
            for (int kvb = 0; kvb < 4; kvb++) {
                U4S8 bv0, bv1;
                bv0.u = *(uint4*)&sVtu[kvb*16 + l15][quad*4];
                bv1.u = *(uint4*)&sVtu[kvb*16 + l15][16 + quad*4];
                O[kvb] = __builtin_amdgcn_mfma_f32_16x16x32_bf16(ap0.s, bv0.s, O[kvb], 0, 0, 0);
                O[kvb] = __builtin_amdgcn_mfma_f32_16x16x32_bf16(ap1.s, bv1.s, O[kvb], 0, 0, 0);
            }
        }
        __syncthreads();
    }

    // epilogue: unnormalized partials, O as bf16
    ushort* ob = (ushort*)opartb;
    #pragma unroll
    for (int r = 0; r < 4; r++) {
        int m = m0 + w*16 + quad*4 + r;
        size_t row = ((size_t)ns * NH + h) * N + m;
        #pragma unroll
        for (int kvb = 0; kvb < 4; kvb++)
            ob[row * 64 + kvb*16 + l15] = f2bu(O[kvb][r]);
        if (l15 == 0) { mpart[row] = M[r]; zpart[row] = Z[r]; }
    }
}

// ---------------------------------------------------------------- k_final2 (merge + logit)
__global__ void __launch_bounds__(128) k_final2(
        const bf16* __restrict__ opartb, const float* __restrict__ mpart,
        const float* __restrict__ zpart, const int* __restrict__ order,
        const float* __restrict__ app, const float* __restrict__ lw,
        const float* __restrict__ lb, const float* __restrict__ sprob,
        float* __restrict__ out)
{
    __shared__ float sWgt[NH][NS];
    __shared__ float sInvZ[NH];
    __shared__ float red[2];
    int m = blockIdx.x, t = threadIdx.x;
    if (t < NH) {
        int h = t;
        float Ms[NS], Mg = -1e30f;
        #pragma unroll
        for (int ns = 0; ns < NS; ns++) {
            Ms[ns] = mpart[(size_t)ns * 16384 + h * 1024 + m];
            Mg = fmaxf(Mg, Ms[ns]);
        }
        float Zt = 0.f;
        #pragma unroll
        for (int ns = 0; ns < NS; ns++) {
            float wgt = __expf(Ms[ns] - Mg);
            sWgt[h][ns] = wgt;
            Zt += zpart[(size_t)ns * 16384 + h * 1024 + m] * wgt;
        }
        sInvZ[h] = 1.0f / Zt;
    }
    __syncthreads();
    int o = order[m];
    const ushort* ob = (const ushort*)opartb;
    float s = 0.f;
    for (int j = t; j < APP; j += 128) {
        int hh = j >> 6, kk = j & 63;
        size_t base = ((size_t)hh * 1024 + m) * 64 + kk;
        float val = 0.f;
        #pragma unroll
        for (int ns = 0; ns < NS; ns++)
            val += bu2f(ob[(size_t)ns * 1048576 + base]) * sWgt[hh][ns];
        float rv = val * sInvZ[hh] + app[o * APP + j];
        s += rv * lw[j];
    }
    #pragma unroll
    for (int off = 32; off > 0; off >>= 1) s += __shfl_down(s, off, 64);
    if ((t & 63) == 0) red[t >> 6] = s;
    __syncthreads();
    if (t == 0) {
        float tot = red[0] + red[1] + lb[0];
        float s1 = 1.0f / (1.0f + expf(-tot));
        out[m] = s1 * sprob[m];
    }
}

// ---------------------------------------------------------------- launch
extern "C" void kernel_launch(void* const* d_in, const int* in_sizes, int n_in,
                              void* d_out, int out_size, void* d_ws, size_t ws_size,
                              hipStream_t stream)
{
    const float* roi      = (const float*)d_in[0];
    const float* cls_loc  = (const float*)d_in[1];
    const float* score    = (const float*)d_in[2];
    const float* app      = (const float*)d_in[3];
    const int*   size     = (const int*)d_in[4];
    const float* rank_w   = (const float*)d_in[5];
    const float* rank_b   = (const float*)d_in[6];
    const float* feat_w   = (const float*)d_in[7];
    const float* feat_b   = (const float*)d_in[8];
    const float* logit_w  = (const float*)d_in[9];
    const float* logit_b  = (const float*)d_in[10];
    const float* wg_w     = (const float*)d_in[11];
    const float* wg_b     = (const float*)d_in[12];
    const float* wk_w     = (const float*)d_in[13];
    const float* wk_b     = (const float*)d_in[14];
    const float* wq_w     = (const float*)d_in[15];
    const float* wq_b     = (const float*)d_in[16];
    const float* wv_w     = (const float*)d_in[17];
    const float* wv_b     = (const float*)d_in[18];
    float* out = (float*)d_out;

    char* ws = (char*)d_ws;
    int*   order = (int*)  (ws + 32768);
    float* sprob = (float*)(ws + 36864);
    float* sbbox = (float*)(ws + 40960);
    bf16*  embb  = (bf16*) (ws + 57344);      // 256 KB
    bf16*  q     = (bf16*) (ws + 8970240);    // 2 MB
    bf16*  k     = (bf16*) (ws + 11067392);   // 2 MB
    bf16*  v     = (bf16*) (ws + 13164544);   // 2 MB
    bf16*  lwbuf = (bf16*) (ws + 17358848);   // 32 MB
    float* part  = (float*)(ws + 50913280);   // 4 MB   [8][1024][128] f32
    bf16*  opartb= (bf16*) (ws + 67690496);   // 8 MB   [NS][16384][64] bf16
    float* mpart = (float*)(ws + 84467712);   // 256 KB [NS][16384]
    float* zpart = (float*)(ws + 84729856);   // 256 KB

    k_prepsort<<<1, 1024, 0, stream>>>(roi, cls_loc, score, size, order, sprob, sbbox, out);
    k_emb4<<<dim3(16, 4, 2), 256, 0, stream>>>(order, app, feat_w, rank_w, part);
    k_embsum<<<512, 256, 0, stream>>>(part, feat_b, rank_b, embb);
    k_qkv2<<<dim3(8, 16, 3), 256, 0, stream>>>(embb, wq_w, wq_b, wk_w, wk_b, wv_w, wv_b, q, k, v);
    k_geo2<<<dim3(1024, 4), 256, 0, stream>>>(sbbox, wg_w, wg_b, lwbuf);
    k_attn4<<<dim3(16, 16, NS), 256, 0, stream>>>(q, k, v, lwbuf, opartb, mpart, zpart);
    k_final2<<<1024, 128, 0, stream>>>(opartb, mpart, zpart, order, app, logit_w, logit_b, sprob, out);
}

// Round 11
// 185.218 us; speedup vs baseline: 1.0523x; 1.0523x over previous
//
#include <hip/hip_runtime.h>
#include <hip/hip_bf16.h>
#include <math.h>

typedef unsigned long long u64;
typedef unsigned int u32;
typedef __hip_bfloat16 bf16;

#define N 1024
#define NCLS 21
#define APP 1024
#define DF 128
#define NH 16
#define DK 64
#define NS 2     // n-splits in flash attention

typedef __attribute__((ext_vector_type(8))) short short8v;
typedef __attribute__((ext_vector_type(4))) float float4v;
union U4S8 { uint4 u; short8v s; };

__device__ __forceinline__ float b2f(bf16 x) { return __bfloat162float(x); }
__device__ __forceinline__ ushort f2bu(float x) { bf16 b = __float2bfloat16(x); return *(ushort*)&b; }
__device__ __forceinline__ float bu2f(ushort u) { return __uint_as_float(((uint)u) << 16); }

// ---------------------------------------------------------------- k_prep
__global__ void k_prep(const float* __restrict__ roi, const float* __restrict__ cls_loc,
                       const float* __restrict__ score, const int* __restrict__ size,
                       float* __restrict__ prob, int* __restrict__ label,
                       float* __restrict__ bbox, u64* __restrict__ keys)
{
    int i = blockIdx.x * 256 + threadIdx.x;
    if (i >= N) return;
    float s[NCLS];
    float mx = -1e30f; int am = 0;
    for (int c = 0; c < NCLS; c++) {
        s[c] = score[i * NCLS + c];
        if (s[c] > mx) { mx = s[c]; am = c; }
    }
    float sum = 0.f;
    for (int c = 0; c < NCLS; c++) sum += expf(s[c] - mx);
    float p = 1.0f / sum;

    float y0 = roi[i*4+0], x0 = roi[i*4+1];
    float y1 = roi[i*4+2], x1 = roi[i*4+3];
    float hh = y1 - y0, ww = x1 - x0;
    float cy = y0 + 0.5f * hh, cx = x0 + 0.5f * ww;
    float l0 = cls_loc[i*84 + am*4 + 0] * 0.1f;
    float l1 = cls_loc[i*84 + am*4 + 1] * 0.1f;
    float l2 = cls_loc[i*84 + am*4 + 2] * 0.2f;
    float l3 = cls_loc[i*84 + am*4 + 3] * 0.2f;
    float ncy = l0 * hh + cy, ncx = l1 * ww + cx;
    float nh = expf(l2) * hh, nw = expf(l3) * ww;
    float b0 = ncy - 0.5f * nh, b1 = ncx - 0.5f * nw;
    float b2v = ncy + 0.5f * nh, b3 = ncx + 0.5f * nw;
    float lim = ((am & 1) == 0) ? (float)size[0] : (float)size[1];
    b0  = fminf(fmaxf(b0, 0.f), lim);
    b1  = fminf(fmaxf(b1, 0.f), lim);
    b2v = fminf(fmaxf(b2v, 0.f), lim);
    b3  = fminf(fmaxf(b3, 0.f), lim);
    prob[i] = p; label[i] = am;
    bbox[i*4+0] = b0; bbox[i*4+1] = b1; bbox[i*4+2] = b2v; bbox[i*4+3] = b3;
    keys[i] = ((u64)(0xFFFFFFFFu - __float_as_uint(p)) << 32) | (u32)i;
}

// ---------------------------------------------------------------- k_rank
__global__ void __launch_bounds__(256) k_rank(
        const u64* __restrict__ keys, const float* __restrict__ prob,
        const int* __restrict__ label, const float* __restrict__ bbox,
        int* __restrict__ order, float* __restrict__ sprob,
        float* __restrict__ sbbox, float* __restrict__ out)
{
    __shared__ u64 sk[N];
    int t = threadIdx.x;
    int i = blockIdx.x * 256 + t;
    for (int j = t; j < N; j += 256) sk[j] = keys[j];
    __syncthreads();
    u64 my = sk[i];
    int r = 0;
    for (int j = 0; j < N; j++) r += (sk[j] < my) ? 1 : 0;
    order[r] = i;
    sprob[r] = prob[i];
    float b0 = bbox[i*4+0], b1 = bbox[i*4+1], b2 = bbox[i*4+2], b3 = bbox[i*4+3];
    sbbox[r*4+0] = b0; sbbox[r*4+1] = b1; sbbox[r*4+2] = b2; sbbox[r*4+3] = b3;
    out[N + r] = (float)(label[i] - 1);
    out[2*N + r*4 + 0] = b0;
    out[2*N + r*4 + 1] = b1;
    out[2*N + r*4 + 2] = b2;
    out[2*N + r*4 + 3] = b3;
}

// ---------------------------------------------------------------- k_emb4 (MFMA, 8 partials)
__global__ void __launch_bounds__(256) k_emb4(
        const int* __restrict__ order, const float* __restrict__ app,
        const float* __restrict__ feat_w, const float* __restrict__ rank_w,
        float* __restrict__ part)
{
    __shared__ ushort sA[64][72];
    __shared__ ushort sW[128][72];
    __shared__ int sOrd[64];
    int rt = blockIdx.x, dg = blockIdx.y, ph = blockIdx.z, t = threadIdx.x;
    int r0 = rt * 64;
    int w = t >> 6, l = t & 63, l15 = l & 15, quad = l >> 4;
    if (t < 64) sOrd[t] = order[r0 + t];
    __syncthreads();

    const float* Wsrc = ph ? rank_w : feat_w;
    float4v acc[8];
    #pragma unroll
    for (int nb = 0; nb < 8; nb++) acc[nb] = (float4v){0.f, 0.f, 0.f, 0.f};

    for (int dc = dg * 4; dc < dg * 4 + 4; dc++) {
        int d0 = dc * 64;
        #pragma unroll
        for (int it = 0; it < 32; it++) {
            int idx = t + it * 256;
            int d = idx >> 7, c = idx & 127;
            sW[c][d] = f2bu(Wsrc[(size_t)(d0 + d) * 128 + c]);
        }
        if (ph == 0) {
            #pragma unroll
            for (int it = 0; it < 16; it++) {
                int idx = t + it * 256;
                int r = idx >> 6, d = idx & 63;
                sA[r][d] = f2bu(app[(size_t)sOrd[r] * 1024 + d0 + d]);
            }
        } else {
            #pragma unroll
            for (int it = 0; it < 16; it++) {
                int idx = t + it * 256;
                int r = idx >> 6, d = idx & 63;
                int dgl = d0 + d;
                float irow = (float)(r0 + r);
                float val;
                if (dgl < 512) val = __sinf(irow * exp2f(-(float)dgl * 0.019464422f));
                else           val = __cosf(irow * exp2f(-(float)(dgl - 512) * 0.019464422f));
                sA[r][d] = f2bu(val);
            }
        }
        __syncthreads();
        U4S8 Af0, Af1;
        Af0.u = *(uint4*)&sA[w*16 + l15][quad*8];
        Af1.u = *(uint4*)&sA[w*16 + l15][32 + quad*8];
        #pragma unroll
        for (int nb = 0; nb < 8; nb++) {
            U4S8 Bf0, Bf1;
            Bf0.u = *(uint4*)&sW[nb*16 + l15][quad*8];
            Bf1.u = *(uint4*)&sW[nb*16 + l15][32 + quad*8];
            acc[nb] = __builtin_amdgcn_mfma_f32_16x16x32_bf16(Af0.s, Bf0.s, acc[nb], 0, 0, 0);
            acc[nb] = __builtin_amdgcn_mfma_f32_16x16x32_bf16(Af1.s, Bf1.s, acc[nb], 0, 0, 0);
        }
        __syncthreads();
    }
    #pragma unroll
    for (int reg = 0; reg < 4; reg++) {
        int row = r0 + w*16 + quad*4 + reg;
        #pragma unroll
        for (int nb = 0; nb < 8; nb++)
            part[(((size_t)ph * 4 + dg) * 1024 + row) * 128 + nb*16 + l15] = acc[nb][reg];
    }
}

// ---------------------------------------------------------------- k_embsum (-> bf16)
__global__ void k_embsum(const float* __restrict__ part,
                         const float* __restrict__ feat_b, const float* __restrict__ rank_b,
                         bf16* __restrict__ embb)
{
    int gid = blockIdx.x * 256 + threadIdx.x;
    int c = gid & 127;
    float acc = feat_b[c] + rank_b[c];
    #pragma unroll
    for (int p8 = 0; p8 < 8; p8++) acc += part[(size_t)p8 * 131072 + gid];
    embb[gid] = __float2bfloat16(acc);
}

// ---------------------------------------------------------------- k_qkv2 (MFMA)
__global__ void __launch_bounds__(256) k_qkv2(
        const bf16* __restrict__ embb,
        const float* __restrict__ wq, const float* __restrict__ bq,
        const float* __restrict__ wk, const float* __restrict__ bk,
        const float* __restrict__ wv, const float* __restrict__ bv,
        bf16* __restrict__ q, bf16* __restrict__ k, bf16* __restrict__ v)
{
    __shared__ ushort sWt[64][136];
    int t = threadIdx.x;
    int rt = blockIdx.x, h = blockIdx.y, mat = blockIdx.z;
    const float* W  = (mat == 0) ? wq : (mat == 1) ? wk : wv;
    const float* Bb = (mat == 0) ? bq : (mat == 1) ? bk : bv;
    bf16* Out       = (mat == 0) ? q  : (mat == 1) ? k  : v;

    #pragma unroll
    for (int i = 0; i < 32; i++) {
        int idx = t + i * 256;
        int d = idx >> 6, kk = idx & 63;
        sWt[kk][d] = f2bu(W[((size_t)h * 128 + d) * 64 + kk]);
    }
    int w = t >> 6, l = t & 63, l15 = l & 15, quad = l >> 4;
    float biasv[4];
    #pragma unroll
    for (int nb = 0; nb < 4; nb++) biasv[nb] = Bb[h * 64 + nb*16 + l15];
    __syncthreads();

    U4S8 Bf[4][4];
    #pragma unroll
    for (int nb = 0; nb < 4; nb++)
        #pragma unroll
        for (int kc = 0; kc < 4; kc++)
            Bf[nb][kc].u = *(uint4*)&sWt[nb*16 + l15][kc*32 + quad*8];

    const uint4* A4 = (const uint4*)embb;
    int r0 = rt * 128 + w * 32;
    ushort* outu = (ushort*)Out;
    for (int mb = 0; mb < 2; mb++) {
        int arow = r0 + mb*16 + l15;
        U4S8 Af[4];
        #pragma unroll
        for (int kc = 0; kc < 4; kc++) Af[kc].u = A4[(size_t)arow * 16 + kc*4 + quad];
        float4v acc[4];
        #pragma unroll
        for (int nb = 0; nb < 4; nb++) acc[nb] = (float4v){0.f, 0.f, 0.f, 0.f};
        #pragma unroll
        for (int kc = 0; kc < 4; kc++)
            #pragma unroll
            for (int nb = 0; nb < 4; nb++)
                acc[nb] = __builtin_amdgcn_mfma_f32_16x16x32_bf16(Af[kc].s, Bf[nb][kc].s, acc[nb], 0, 0, 0);
        #pragma unroll
        for (int reg = 0; reg < 4; reg++) {
            int orow = r0 + mb*16 + quad*4 + reg;
            #pragma unroll
            for (int nb = 0; nb < 4; nb++)
                outu[((size_t)h * N + orow) * 64 + nb*16 + l15] = f2bu(acc[nb][reg] + biasv[nb]);
        }
    }
}

// ---------------------------------------------------------------- k_geo2 (MFMA head-projection)
__global__ void __launch_bounds__(256) k_geo2(
        const float* __restrict__ sbbox, const float* __restrict__ wgw,
        const float* __restrict__ wgb, bf16* __restrict__ lw)
{
    __shared__ ushort sE[256][72];
    __shared__ uint   sOut[NH][132];
    __shared__ float  mbb[4];
    int m = blockIdx.x, nc = blockIdx.y, t = threadIdx.x;
    int w = t >> 6, l = t & 63, l15 = l & 15, quad = l >> 4;

    if (t == 0) {
        float b0 = sbbox[m*4+0], b1 = sbbox[m*4+1], b2 = sbbox[m*4+2], b3 = sbbox[m*4+3];
        mbb[0] = (b0 + b2) * 0.5f; mbb[1] = (b1 + b3) * 0.5f;
        mbb[2] = b2 - b0 + 1.0f;   mbb[3] = b3 - b1 + 1.0f;
    }
    U4S8 Bg0, Bg1;
    #pragma unroll
    for (int j = 0; j < 8; j++) {
        ((ushort*)&Bg0)[j] = f2bu(wgw[l15*64 + quad*8 + j]);
        ((ushort*)&Bg1)[j] = f2bu(wgw[l15*64 + 32 + quad*8 + j]);
    }
    float bias = wgb[l15];
    __syncthreads();

    int n = nc * 256 + t;
    float b0 = sbbox[n*4+0], b1 = sbbox[n*4+1], b2 = sbbox[n*4+2], b3 = sbbox[n*4+3];
    float cxn = (b0 + b2) * 0.5f, cyn = (b1 + b3) * 0.5f;
    float wn = b2 - b0 + 1.0f, hn = b3 - b1 + 1.0f;
    float dx = __logf(fmaxf(fabsf((mbb[0] - cxn) / mbb[2]), 1e-3f));
    float dy = __logf(fmaxf(fabsf((mbb[1] - cyn) / mbb[3]), 1e-3f));
    float dw = __logf(mbb[2] / wn);
    float dh = __logf(mbb[3] / hn);
    float pos[4] = { dx, dy, dw, dh };
    const float dmt[8] = { 1.0f, 0.42169650342f, 0.177827941f, 0.0749894209f,
                           0.0316227766f, 0.01333521432f, 0.00562341325f, 0.00237137371f };
    float args[32];
    #pragma unroll
    for (int c = 0; c < 4; c++)
        #pragma unroll
        for (int f = 0; f < 8; f++) args[c*8 + f] = 100.0f * pos[c] * dmt[f];
    uint* rowp = (uint*)&sE[t][0];
    #pragma unroll
    for (int jj = 0; jj < 16; jj++) {
        float s0 = __sinf(args[2*jj]), s1 = __sinf(args[2*jj+1]);
        rowp[jj] = (uint)f2bu(s0) | ((uint)f2bu(s1) << 16);
    }
    #pragma unroll
    for (int jj = 0; jj < 16; jj++) {
        float c0 = __cosf(args[2*jj]), c1 = __cosf(args[2*jj+1]);
        rowp[16 + jj] = (uint)f2bu(c0) | ((uint)f2bu(c1) << 16);
    }
    __syncthreads();

    #pragma unroll
    for (int mt2 = 0; mt2 < 4; mt2++) {
        int prow = w*64 + mt2*16 + l15;
        U4S8 Af0, Af1;
        Af0.u = *(uint4*)&sE[prow][quad*8];
        Af1.u = *(uint4*)&sE[prow][32 + quad*8];
        float4v c = (float4v){0.f, 0.f, 0.f, 0.f};
        c = __builtin_amdgcn_mfma_f32_16x16x32_bf16(Af0.s, Bg0.s, c, 0, 0, 0);
        c = __builtin_amdgcn_mfma_f32_16x16x32_bf16(Af1.s, Bg1.s, c, 0, 0, 0);
        float v0 = __logf(fmaxf(fmaxf(c[0] + bias, 0.f), 1e-6f));
        float v1 = __logf(fmaxf(fmaxf(c[1] + bias, 0.f), 1e-6f));
        float v2 = __logf(fmaxf(fmaxf(c[2] + bias, 0.f), 1e-6f));
        float v3 = __logf(fmaxf(fmaxf(c[3] + bias, 0.f), 1e-6f));
        int pb = (w*64 + mt2*16 + quad*4) >> 1;
        sOut[l15][pb]     = (uint)f2bu(v0) | ((uint)f2bu(v1) << 16);
        sOut[l15][pb + 1] = (uint)f2bu(v2) | ((uint)f2bu(v3) << 16);
    }
    __syncthreads();
    uint* lwu = (uint*)lw;
    #pragma unroll
    for (int it = 0; it < 8; it++) {
        int idx = t + it * 256;
        int hh = idx >> 7, col = idx & 127;
        lwu[((size_t)hh << 19) + ((size_t)m << 9) + nc*128 + col] = sOut[hh][col];
    }
}

// ---------------------------------------------------------------- k_attn4 (MFMA flash, n-split)
__global__ void __launch_bounds__(256) k_attn4(
        const bf16* __restrict__ q, const bf16* __restrict__ kmat,
        const bf16* __restrict__ v, const bf16* __restrict__ lw,
        bf16* __restrict__ opartb, float* __restrict__ mpart, float* __restrict__ zpart)
{
    __shared__ uint sQu[64][36];
    __shared__ uint sVtu[64][36];
    __shared__ uint slwu[64][36];
    __shared__ uint sPu[4][16][36];

    int t = threadIdx.x;
    int mt = blockIdx.x, h = blockIdx.y, ns = blockIdx.z;
    int m0 = mt * 64;
    int w = t >> 6, l = t & 63, l15 = l & 15, quad = l >> 4;

    U4S8 kf0, kf1;
    {
        const uint4* k4 = (const uint4*)kmat;
        size_t krow = ((size_t)h * N + m0 + w*16 + l15) * 8;
        kf0.u = k4[krow + quad];
        kf1.u = k4[krow + 4 + quad];
    }

    float4v O[4];
    float M[4], Z[4];
    #pragma unroll
    for (int i = 0; i < 4; i++) {
        O[i] = (float4v){0.f, 0.f, 0.f, 0.f};
        M[i] = -1e30f; Z[i] = 0.f;
    }

    const uint* qsrc = (const uint*)q;
    const uint* vsrc = (const uint*)v;
    const uint* lwsrc = (const uint*)lw;

    for (int tile = ns * (16/NS); tile < (ns + 1) * (16/NS); tile++) {
        int n0 = tile * 64;
        #pragma unroll
        for (int i = 0; i < 8; i++) {
            int idx = t + i * 256;
            int nj = idx >> 5, kp = idx & 31;
            sQu[nj][kp] = qsrc[((size_t)h * N + n0 + nj) * 32 + kp];
        }
        #pragma unroll
        for (int i = 0; i < 4; i++) {
            int idx = t + i * 256;
            int a = idx & 31, nh2 = idx >> 5;
            uint g0 = vsrc[((size_t)h * N + n0 + 2*nh2) * 32 + a];
            uint g1 = vsrc[((size_t)h * N + n0 + 2*nh2 + 1) * 32 + a];
            sVtu[2*a][nh2]     = (g0 & 0xFFFFu) | (g1 << 16);
            sVtu[2*a + 1][nh2] = (g0 >> 16) | (g1 & 0xFFFF0000u);
        }
        #pragma unroll
        for (int i = 0; i < 8; i++) {
            int idx = t + i * 256;
            int mi = idx >> 5, np = idx & 31;
            slwu[mi][np] = lwsrc[((size_t)h << 19) + ((size_t)(m0 + mi) << 9) + (n0 >> 1) + np];
        }
        __syncthreads();

        float4v S[4];
        #pragma unroll
        for (int nb = 0; nb < 4; nb++) {
            U4S8 bq0, bq1;
            bq0.u = *(uint4*)&sQu[nb*16 + l15][quad*4];
            bq1.u = *(uint4*)&sQu[nb*16 + l15][16 + quad*4];
            float4v zz = (float4v){0.f, 0.f, 0.f, 0.f};
            float4v p0 = __builtin_amdgcn_mfma_f32_16x16x32_bf16(kf0.s, bq0.s, zz, 0, 0, 0);
            S[nb] = __builtin_amdgcn_mfma_f32_16x16x32_bf16(kf1.s, bq1.s, p0, 0, 0, 0);
        }
        ushort* pRow[4];
        #pragma unroll
        for (int r = 0; r < 4; r++) pRow[r] = (ushort*)&sPu[w][quad*4 + r][0];
        #pragma unroll
        for (int r = 0; r < 4; r++) {
            int mi = w*16 + quad*4 + r;
            float sv[4];
            #pragma unroll
            for (int nb = 0; nb < 4; nb++) {
                int col = nb*16 + l15;
                uint lu = slwu[mi][col >> 1];
                float lv = (col & 1) ? __uint_as_float(lu & 0xFFFF0000u)
                                     : __uint_as_float(lu << 16);
                sv[nb] = S[nb][r] * 0.125f + lv;
            }
            float rm = fmaxf(fmaxf(sv[0], sv[1]), fmaxf(sv[2], sv[3]));
            #pragma unroll
            for (int off = 1; off < 16; off <<= 1)
                rm = fmaxf(rm, __shfl_xor(rm, off, 64));
            float newM = fmaxf(M[r], rm);
            float pr[4], rs = 0.f;
            #pragma unroll
            for (int nb = 0; nb < 4; nb++) {
                pr[nb] = __expf(sv[nb] - newM);
                rs += pr[nb];
            }
            #pragma unroll
            for (int off = 1; off < 16; off <<= 1)
                rs += __shfl_xor(rs, off, 64);
            float sc = __expf(M[r] - newM);
            M[r] = newM;
            Z[r] = Z[r] * sc + rs;
            #pragma unroll
            for (int kvb = 0; kvb < 4; kvb++) O[kvb][r] *= sc;
            #pragma unroll
            for (int nb = 0; nb < 4; nb++)
                pRow[r][nb*16 + l15] = f2bu(pr[nb]);
        }
        {
            U4S8 ap0, ap1;
            ap0.u = *(uint4*)&sPu[w][l15][quad*4];
            ap1.u = *(uint4*)&sPu[w][l15][16 + quad*4];
            #pragma unroll
            for (int kvb = 0; kvb < 4; kvb++) {
                U4S8 bv0, bv1;
                bv0.u = *(uint4*)&sVtu[kvb*16 + l15][quad*4];
                bv1.u = *(uint4*)&sVtu[kvb*16 + l15][16 + quad*4];
                O[kvb] = __builtin_amdgcn_mfma_f32_16x16x32_bf16(ap0.s, bv0.s, O[kvb], 0, 0, 0);
                O[kvb] = __builtin_amdgcn_mfma_f32_16x16x32_bf16(ap1.s, bv1.s, O[kvb], 0, 0, 0);
            }
        }
        __syncthreads();
    }

    ushort* ob = (ushort*)opartb;
    #pragma unroll
    for (int r = 0; r < 4; r++) {
        int m = m0 + w*16 + quad*4 + r;
        size_t row = ((size_t)ns * NH + h) * N + m;
        #pragma unroll
        for (int kvb = 0; kvb < 4; kvb++)
            ob[row * 64 + kvb*16 + l15] = f2bu(O[kvb][r]);
        if (l15 == 0) { mpart[row] = M[r]; zpart[row] = Z[r]; }
    }
}

// ---------------------------------------------------------------- k_final2 (merge + logit)
__global__ void __launch_bounds__(128) k_final2(
        const bf16* __restrict__ opartb, const float* __restrict__ mpart,
        const float* __restrict__ zpart, const int* __restrict__ order,
        const float* __restrict__ app, const float* __restrict__ lw,
        const float* __restrict__ lb, const float* __restrict__ sprob,
        float* __restrict__ out)
{
    __shared__ float sWgt[NH][NS];
    __shared__ float sInvZ[NH];
    __shared__ float red[2];
    int m = blockIdx.x, t = threadIdx.x;
    if (t < NH) {
        int h = t;
        float Ms[NS], Mg = -1e30f;
        #pragma unroll
        for (int ns = 0; ns < NS; ns++) {
            Ms[ns] = mpart[(size_t)ns * 16384 + h * 1024 + m];
            Mg = fmaxf(Mg, Ms[ns]);
        }
        float Zt = 0.f;
        #pragma unroll
        for (int ns = 0; ns < NS; ns++) {
            float wgt = __expf(Ms[ns] - Mg);
            sWgt[h][ns] = wgt;
            Zt += zpart[(size_t)ns * 16384 + h * 1024 + m] * wgt;
        }
        sInvZ[h] = 1.0f / Zt;
    }
    __syncthreads();
    int o = order[m];
    const ushort* ob = (const ushort*)opartb;
    float s = 0.f;
    for (int j = t; j < APP; j += 128) {
        int hh = j >> 6, kk = j & 63;
        size_t base = ((size_t)hh * 1024 + m) * 64 + kk;
        float val = 0.f;
        #pragma unroll
        for (int ns = 0; ns < NS; ns++)
            val += bu2f(ob[(size_t)ns * 1048576 + base]) * sWgt[hh][ns];
        float rv = val * sInvZ[hh] + app[o * APP + j];
        s += rv * lw[j];
    }
    #pragma unroll
    for (int off = 32; off > 0; off >>= 1) s += __shfl_down(s, off, 64);
    if ((t & 63) == 0) red[t >> 6] = s;
    __syncthreads();
    if (t == 0) {
        float tot = red[0] + red[1] + lb[0];
        float s1 = 1.0f / (1.0f + expf(-tot));
        out[m] = s1 * sprob[m];
    }
}

// ---------------------------------------------------------------- launch
extern "C" void kernel_launch(void* const* d_in, const int* in_sizes, int n_in,
                              void* d_out, int out_size, void* d_ws, size_t ws_size,
                              hipStream_t stream)
{
    const float* roi      = (const float*)d_in[0];
    const float* cls_loc  = (const float*)d_in[1];
    const float* score    = (const float*)d_in[2];
    const float* app      = (const float*)d_in[3];
    const int*   size     = (const int*)d_in[4];
    const float* rank_w   = (const float*)d_in[5];
    const float* rank_b   = (const float*)d_in[6];
    const float* feat_w   = (const float*)d_in[7];
    const float* feat_b   = (const float*)d_in[8];
    const float* logit_w  = (const float*)d_in[9];
    const float* logit_b  = (const float*)d_in[10];
    const float* wg_w     = (const float*)d_in[11];
    const float* wg_b     = (const float*)d_in[12];
    const float* wk_w     = (const float*)d_in[13];
    const float* wk_b     = (const float*)d_in[14];
    const float* wq_w     = (const float*)d_in[15];
    const float* wq_b     = (const float*)d_in[16];
    const float* wv_w     = (const float*)d_in[17];
    const float* wv_b     = (const float*)d_in[18];
    float* out = (float*)d_out;

    char* ws = (char*)d_ws;
    float* prob  = (float*)(ws + 0);
    int*   label = (int*)  (ws + 4096);
    float* bbox  = (float*)(ws + 8192);
    u64*   keys  = (u64*)  (ws + 24576);
    int*   order = (int*)  (ws + 32768);
    float* sprob = (float*)(ws + 36864);
    float* sbbox = (float*)(ws + 40960);
    bf16*  embb  = (bf16*) (ws + 57344);      // 256 KB
    bf16*  q     = (bf16*) (ws + 8970240);    // 2 MB
    bf16*  k     = (bf16*) (ws + 11067392);   // 2 MB
    bf16*  v     = (bf16*) (ws + 13164544);   // 2 MB
    bf16*  lwbuf = (bf16*) (ws + 17358848);   // 32 MB
    float* part  = (float*)(ws + 50913280);   // 4 MB   [8][1024][128] f32
    bf16*  opartb= (bf16*) (ws + 67690496);   // 4 MB   [NS][16384][64] bf16
    float* mpart = (float*)(ws + 84467712);   // 128 KB [NS][16384]
    float* zpart = (float*)(ws + 84729856);   // 128 KB

    k_prep<<<4, 256, 0, stream>>>(roi, cls_loc, score, size, prob, label, bbox, keys);
    k_rank<<<4, 256, 0, stream>>>(keys, prob, label, bbox, order, sprob, sbbox, out);
    k_emb4<<<dim3(16, 4, 2), 256, 0, stream>>>(order, app, feat_w, rank_w, part);
    k_embsum<<<512, 256, 0, stream>>>(part, feat_b, rank_b, embb);
    k_qkv2<<<dim3(8, 16, 3), 256, 0, stream>>>(embb, wq_w, wq_b, wk_w, wk_b, wv_w, wv_b, q, k, v);
    k_geo2<<<dim3(1024, 4), 256, 0, stream>>>(sbbox, wg_w, wg_b, lwbuf);
    k_attn4<<<dim3(16, 16, NS), 256, 0, stream>>>(q, k, v, lwbuf, opartb, mpart, zpart);
    k_final2<<<1024, 128, 0, stream>>>(opartb, mpart, zpart, order, app, logit_w, logit_b, sprob, out);
}

// Round 12
// 183.682 us; speedup vs baseline: 1.0611x; 1.0084x over previous
//
#include <hip/hip_runtime.h>
#include <hip/hip_bf16.h>
#include <math.h>

typedef unsigned long long u64;
typedef unsigned int u32;
typedef __hip_bfloat16 bf16;

#define N 1024
#define NCLS 21
#define APP 1024
#define DF 128
#define NH 16
#define DK 64
#define NS 2     // n-splits in flash attention

typedef __attribute__((ext_vector_type(8))) short short8v;
typedef __attribute__((ext_vector_type(4))) float float4v;
union U4S8 { uint4 u; short8v s; };

__device__ __forceinline__ float b2f(bf16 x) { return __bfloat162float(x); }
__device__ __forceinline__ ushort f2bu(float x) { bf16 b = __float2bfloat16(x); return *(ushort*)&b; }
__device__ __forceinline__ float bu2f(ushort u) { return __uint_as_float(((uint)u) << 16); }

// ---------------------------------------------------------------- k_prep
__global__ void k_prep(const float* __restrict__ roi, const float* __restrict__ cls_loc,
                       const float* __restrict__ score, const int* __restrict__ size,
                       float* __restrict__ prob, int* __restrict__ label,
                       float* __restrict__ bbox, u64* __restrict__ keys)
{
    int i = blockIdx.x * 256 + threadIdx.x;
    if (i >= N) return;
    float s[NCLS];
    float mx = -1e30f; int am = 0;
    for (int c = 0; c < NCLS; c++) {
        s[c] = score[i * NCLS + c];
        if (s[c] > mx) { mx = s[c]; am = c; }
    }
    float sum = 0.f;
    for (int c = 0; c < NCLS; c++) sum += expf(s[c] - mx);
    float p = 1.0f / sum;

    float y0 = roi[i*4+0], x0 = roi[i*4+1];
    float y1 = roi[i*4+2], x1 = roi[i*4+3];
    float hh = y1 - y0, ww = x1 - x0;
    float cy = y0 + 0.5f * hh, cx = x0 + 0.5f * ww;
    float l0 = cls_loc[i*84 + am*4 + 0] * 0.1f;
    float l1 = cls_loc[i*84 + am*4 + 1] * 0.1f;
    float l2 = cls_loc[i*84 + am*4 + 2] * 0.2f;
    float l3 = cls_loc[i*84 + am*4 + 3] * 0.2f;
    float ncy = l0 * hh + cy, ncx = l1 * ww + cx;
    float nh = expf(l2) * hh, nw = expf(l3) * ww;
    float b0 = ncy - 0.5f * nh, b1 = ncx - 0.5f * nw;
    float b2v = ncy + 0.5f * nh, b3 = ncx + 0.5f * nw;
    float lim = ((am & 1) == 0) ? (float)size[0] : (float)size[1];
    b0  = fminf(fmaxf(b0, 0.f), lim);
    b1  = fminf(fmaxf(b1, 0.f), lim);
    b2v = fminf(fmaxf(b2v, 0.f), lim);
    b3  = fminf(fmaxf(b3, 0.f), lim);
    prob[i] = p; label[i] = am;
    bbox[i*4+0] = b0; bbox[i*4+1] = b1; bbox[i*4+2] = b2v; bbox[i*4+3] = b3;
    keys[i] = ((u64)(0xFFFFFFFFu - __float_as_uint(p)) << 32) | (u32)i;
}

// ---------------------------------------------------------------- k_rank
__global__ void __launch_bounds__(256) k_rank(
        const u64* __restrict__ keys, const float* __restrict__ prob,
        const int* __restrict__ label, const float* __restrict__ bbox,
        int* __restrict__ order, float* __restrict__ sprob,
        float* __restrict__ sbbox, float* __restrict__ out)
{
    __shared__ u64 sk[N];
    int t = threadIdx.x;
    int i = blockIdx.x * 256 + t;
    for (int j = t; j < N; j += 256) sk[j] = keys[j];
    __syncthreads();
    u64 my = sk[i];
    int r = 0;
    for (int j = 0; j < N; j++) r += (sk[j] < my) ? 1 : 0;
    order[r] = i;
    sprob[r] = prob[i];
    float b0 = bbox[i*4+0], b1 = bbox[i*4+1], b2 = bbox[i*4+2], b3 = bbox[i*4+3];
    sbbox[r*4+0] = b0; sbbox[r*4+1] = b1; sbbox[r*4+2] = b2; sbbox[r*4+3] = b3;
    out[N + r] = (float)(label[i] - 1);
    out[2*N + r*4 + 0] = b0;
    out[2*N + r*4 + 1] = b1;
    out[2*N + r*4 + 2] = b2;
    out[2*N + r*4 + 3] = b3;
}

// ---------------------------------------------------------------- k_geoemb (horizontal fusion)
// blocks 0..4095: geo body (m = bx>>2, nc = bx&3) -> lw
// blocks 4096..4223: emb body (128 blocks: rt/dg/ph) -> part
__global__ void __launch_bounds__(256) k_geoemb(
        const int* __restrict__ order, const float* __restrict__ app,
        const float* __restrict__ feat_w, const float* __restrict__ rank_w,
        float* __restrict__ part,
        const float* __restrict__ sbbox, const float* __restrict__ wgw,
        const float* __restrict__ wgb, bf16* __restrict__ lw)
{
    __shared__ __align__(16) char smem[45328];
    int bx = blockIdx.x, t = threadIdx.x;
    int w = t >> 6, l = t & 63, l15 = l & 15, quad = l >> 4;

    if (bx < 4096) {
        // ===================== geo body =====================
        ushort (*sE)[72]  = (ushort(*)[72])smem;           // 36864 B
        uint   (*sOut)[132] = (uint(*)[132])(smem + 36864); // 8448 B
        float* mbb = (float*)(smem + 45312);                // 16 B
        int m = bx >> 2, nc = bx & 3;

        if (t == 0) {
            float b0 = sbbox[m*4+0], b1 = sbbox[m*4+1], b2 = sbbox[m*4+2], b3 = sbbox[m*4+3];
            mbb[0] = (b0 + b2) * 0.5f; mbb[1] = (b1 + b3) * 0.5f;
            mbb[2] = b2 - b0 + 1.0f;   mbb[3] = b3 - b1 + 1.0f;
        }
        U4S8 Bg0, Bg1;
        #pragma unroll
        for (int j = 0; j < 8; j++) {
            ((ushort*)&Bg0)[j] = f2bu(wgw[l15*64 + quad*8 + j]);
            ((ushort*)&Bg1)[j] = f2bu(wgw[l15*64 + 32 + quad*8 + j]);
        }
        float bias = wgb[l15];
        __syncthreads();

        int n = nc * 256 + t;
        float b0 = sbbox[n*4+0], b1 = sbbox[n*4+1], b2 = sbbox[n*4+2], b3 = sbbox[n*4+3];
        float cxn = (b0 + b2) * 0.5f, cyn = (b1 + b3) * 0.5f;
        float wn = b2 - b0 + 1.0f, hn = b3 - b1 + 1.0f;
        float dx = __logf(fmaxf(fabsf((mbb[0] - cxn) / mbb[2]), 1e-3f));
        float dy = __logf(fmaxf(fabsf((mbb[1] - cyn) / mbb[3]), 1e-3f));
        float dw = __logf(mbb[2] / wn);
        float dh = __logf(mbb[3] / hn);
        float pos[4] = { dx, dy, dw, dh };
        const float dmt[8] = { 1.0f, 0.42169650342f, 0.177827941f, 0.0749894209f,
                               0.0316227766f, 0.01333521432f, 0.00562341325f, 0.00237137371f };
        float args[32];
        #pragma unroll
        for (int c = 0; c < 4; c++)
            #pragma unroll
            for (int f = 0; f < 8; f++) args[c*8 + f] = 100.0f * pos[c] * dmt[f];
        uint* rowp = (uint*)&sE[t][0];
        #pragma unroll
        for (int jj = 0; jj < 16; jj++) {
            float s0 = __sinf(args[2*jj]), s1 = __sinf(args[2*jj+1]);
            rowp[jj] = (uint)f2bu(s0) | ((uint)f2bu(s1) << 16);
        }
        #pragma unroll
        for (int jj = 0; jj < 16; jj++) {
            float c0 = __cosf(args[2*jj]), c1 = __cosf(args[2*jj+1]);
            rowp[16 + jj] = (uint)f2bu(c0) | ((uint)f2bu(c1) << 16);
        }
        __syncthreads();

        #pragma unroll
        for (int mt2 = 0; mt2 < 4; mt2++) {
            int prow = w*64 + mt2*16 + l15;
            U4S8 Af0, Af1;
            Af0.u = *(uint4*)&sE[prow][quad*8];
            Af1.u = *(uint4*)&sE[prow][32 + quad*8];
            float4v c = (float4v){0.f, 0.f, 0.f, 0.f};
            c = __builtin_amdgcn_mfma_f32_16x16x32_bf16(Af0.s, Bg0.s, c, 0, 0, 0);
            c = __builtin_amdgcn_mfma_f32_16x16x32_bf16(Af1.s, Bg1.s, c, 0, 0, 0);
            float v0 = __logf(fmaxf(fmaxf(c[0] + bias, 0.f), 1e-6f));
            float v1 = __logf(fmaxf(fmaxf(c[1] + bias, 0.f), 1e-6f));
            float v2 = __logf(fmaxf(fmaxf(c[2] + bias, 0.f), 1e-6f));
            float v3 = __logf(fmaxf(fmaxf(c[3] + bias, 0.f), 1e-6f));
            int pb = (w*64 + mt2*16 + quad*4) >> 1;
            sOut[l15][pb]     = (uint)f2bu(v0) | ((uint)f2bu(v1) << 16);
            sOut[l15][pb + 1] = (uint)f2bu(v2) | ((uint)f2bu(v3) << 16);
        }
        __syncthreads();
        uint* lwu = (uint*)lw;
        #pragma unroll
        for (int it = 0; it < 8; it++) {
            int idx = t + it * 256;
            int hh = idx >> 7, col = idx & 127;
            lwu[((size_t)hh << 19) + ((size_t)m << 9) + nc*128 + col] = sOut[hh][col];
        }
    } else {
        // ===================== emb body =====================
        ushort (*sA)[72] = (ushort(*)[72])smem;             // 9216 B
        ushort (*sW)[72] = (ushort(*)[72])(smem + 9216);    // 18432 B
        int* sOrd = (int*)(smem + 27648);                   // 256 B
        int idx0 = bx - 4096;
        int rt = idx0 & 15, dg = (idx0 >> 4) & 3, ph = idx0 >> 6;
        int r0 = rt * 64;
        if (t < 64) sOrd[t] = order[r0 + t];
        __syncthreads();

        const float* Wsrc = ph ? rank_w : feat_w;
        float4v acc[8];
        #pragma unroll
        for (int nb = 0; nb < 8; nb++) acc[nb] = (float4v){0.f, 0.f, 0.f, 0.f};

        for (int dc = dg * 4; dc < dg * 4 + 4; dc++) {
            int d0 = dc * 64;
            #pragma unroll
            for (int it = 0; it < 32; it++) {
                int idx = t + it * 256;
                int d = idx >> 7, c = idx & 127;
                sW[c][d] = f2bu(Wsrc[(size_t)(d0 + d) * 128 + c]);
            }
            if (ph == 0) {
                #pragma unroll
                for (int it = 0; it < 16; it++) {
                    int idx = t + it * 256;
                    int r = idx >> 6, d = idx & 63;
                    sA[r][d] = f2bu(app[(size_t)sOrd[r] * 1024 + d0 + d]);
                }
            } else {
                #pragma unroll
                for (int it = 0; it < 16; it++) {
                    int idx = t + it * 256;
                    int r = idx >> 6, d = idx & 63;
                    int dgl = d0 + d;
                    float irow = (float)(r0 + r);
                    float val;
                    if (dgl < 512) val = __sinf(irow * exp2f(-(float)dgl * 0.019464422f));
                    else           val = __cosf(irow * exp2f(-(float)(dgl - 512) * 0.019464422f));
                    sA[r][d] = f2bu(val);
                }
            }
            __syncthreads();
            U4S8 Af0, Af1;
            Af0.u = *(uint4*)&sA[w*16 + l15][quad*8];
            Af1.u = *(uint4*)&sA[w*16 + l15][32 + quad*8];
            #pragma unroll
            for (int nb = 0; nb < 8; nb++) {
                U4S8 Bf0, Bf1;
                Bf0.u = *(uint4*)&sW[nb*16 + l15][quad*8];
                Bf1.u = *(uint4*)&sW[nb*16 + l15][32 + quad*8];
                acc[nb] = __builtin_amdgcn_mfma_f32_16x16x32_bf16(Af0.s, Bf0.s, acc[nb], 0, 0, 0);
                acc[nb] = __builtin_amdgcn_mfma_f32_16x16x32_bf16(Af1.s, Bf1.s, acc[nb], 0, 0, 0);
            }
            __syncthreads();
        }
        #pragma unroll
        for (int reg = 0; reg < 4; reg++) {
            int row = r0 + w*16 + quad*4 + reg;
            #pragma unroll
            for (int nb = 0; nb < 8; nb++)
                part[(((size_t)ph * 4 + dg) * 1024 + row) * 128 + nb*16 + l15] = acc[nb][reg];
        }
    }
}

// ---------------------------------------------------------------- k_embsum (-> bf16)
__global__ void k_embsum(const float* __restrict__ part,
                         const float* __restrict__ feat_b, const float* __restrict__ rank_b,
                         bf16* __restrict__ embb)
{
    int gid = blockIdx.x * 256 + threadIdx.x;
    int c = gid & 127;
    float acc = feat_b[c] + rank_b[c];
    #pragma unroll
    for (int p8 = 0; p8 < 8; p8++) acc += part[(size_t)p8 * 131072 + gid];
    embb[gid] = __float2bfloat16(acc);
}

// ---------------------------------------------------------------- k_qkv2 (MFMA)
__global__ void __launch_bounds__(256) k_qkv2(
        const bf16* __restrict__ embb,
        const float* __restrict__ wq, const float* __restrict__ bq,
        const float* __restrict__ wk, const float* __restrict__ bk,
        const float* __restrict__ wv, const float* __restrict__ bv,
        bf16* __restrict__ q, bf16* __restrict__ k, bf16* __restrict__ v)
{
    __shared__ ushort sWt[64][136];
    int t = threadIdx.x;
    int rt = blockIdx.x, h = blockIdx.y, mat = blockIdx.z;
    const float* W  = (mat == 0) ? wq : (mat == 1) ? wk : wv;
    const float* Bb = (mat == 0) ? bq : (mat == 1) ? bk : bv;
    bf16* Out       = (mat == 0) ? q  : (mat == 1) ? k  : v;

    #pragma unroll
    for (int i = 0; i < 32; i++) {
        int idx = t + i * 256;
        int d = idx >> 6, kk = idx & 63;
        sWt[kk][d] = f2bu(W[((size_t)h * 128 + d) * 64 + kk]);
    }
    int w = t >> 6, l = t & 63, l15 = l & 15, quad = l >> 4;
    float biasv[4];
    #pragma unroll
    for (int nb = 0; nb < 4; nb++) biasv[nb] = Bb[h * 64 + nb*16 + l15];
    __syncthreads();

    U4S8 Bf[4][4];
    #pragma unroll
    for (int nb = 0; nb < 4; nb++)
        #pragma unroll
        for (int kc = 0; kc < 4; kc++)
            Bf[nb][kc].u = *(uint4*)&sWt[nb*16 + l15][kc*32 + quad*8];

    const uint4* A4 = (const uint4*)embb;
    int r0 = rt * 128 + w * 32;
    ushort* outu = (ushort*)Out;
    for (int mb = 0; mb < 2; mb++) {
        int arow = r0 + mb*16 + l15;
        U4S8 Af[4];
        #pragma unroll
        for (int kc = 0; kc < 4; kc++) Af[kc].u = A4[(size_t)arow * 16 + kc*4 + quad];
        float4v acc[4];
        #pragma unroll
        for (int nb = 0; nb < 4; nb++) acc[nb] = (float4v){0.f, 0.f, 0.f, 0.f};
        #pragma unroll
        for (int kc = 0; kc < 4; kc++)
            #pragma unroll
            for (int nb = 0; nb < 4; nb++)
                acc[nb] = __builtin_amdgcn_mfma_f32_16x16x32_bf16(Af[kc].s, Bf[nb][kc].s, acc[nb], 0, 0, 0);
        #pragma unroll
        for (int reg = 0; reg < 4; reg++) {
            int orow = r0 + mb*16 + quad*4 + reg;
            #pragma unroll
            for (int nb = 0; nb < 4; nb++)
                outu[((size_t)h * N + orow) * 64 + nb*16 + l15] = f2bu(acc[nb][reg] + biasv[nb]);
        }
    }
}

// ---------------------------------------------------------------- k_attn4 (MFMA flash, n-split)
__global__ void __launch_bounds__(256) k_attn4(
        const bf16* __restrict__ q, const bf16* __restrict__ kmat,
        const bf16* __restrict__ v, const bf16* __restrict__ lw,
        bf16* __restrict__ opartb, float* __restrict__ mpart, float* __restrict__ zpart)
{
    __shared__ uint sQu[64][36];
    __shared__ uint sVtu[64][36];
    __shared__ uint slwu[64][36];
    __shared__ uint sPu[4][16][36];

    int t = threadIdx.x;
    int mt = blockIdx.x, h = blockIdx.y, ns = blockIdx.z;
    int m0 = mt * 64;
    int w = t >> 6, l = t & 63, l15 = l & 15, quad = l >> 4;

    U4S8 kf0, kf1;
    {
        const uint4* k4 = (const uint4*)kmat;
        size_t krow = ((size_t)h * N + m0 + w*16 + l15) * 8;
        kf0.u = k4[krow + quad];
        kf1.u = k4[krow + 4 + quad];
    }

    float4v O[4];
    float M[4], Z[4];
    #pragma unroll
    for (int i = 0; i < 4; i++) {
        O[i] = (float4v){0.f, 0.f, 0.f, 0.f};
        M[i] = -1e30f; Z[i] = 0.f;
    }

    const uint* qsrc = (const uint*)q;
    const uint* vsrc = (const uint*)v;
    const uint* lwsrc = (const uint*)lw;

    for (int tile = ns * (16/NS); tile < (ns + 1) * (16/NS); tile++) {
        int n0 = tile * 64;
        #pragma unroll
        for (int i = 0; i < 8; i++) {
            int idx = t + i * 256;
            int nj = idx >> 5, kp = idx & 31;
            sQu[nj][kp] = qsrc[((size_t)h * N + n0 + nj) * 32 + kp];
        }
        #pragma unroll
        for (int i = 0; i < 4; i++) {
            int idx = t + i * 256;
            int a = idx & 31, nh2 = idx >> 5;
            uint g0 = vsrc[((size_t)h * N + n0 + 2*nh2) * 32 + a];
            uint g1 = vsrc[((size_t)h * N + n0 + 2*nh2 + 1) * 32 + a];
            sVtu[2*a][nh2]     = (g0 & 0xFFFFu) | (g1 << 16);
            sVtu[2*a + 1][nh2] = (g0 >> 16) | (g1 & 0xFFFF0000u);
        }
        #pragma unroll
        for (int i = 0; i < 8; i++) {
            int idx = t + i * 256;
            int mi = idx >> 5, np = idx & 31;
            slwu[mi][np] = lwsrc[((size_t)h << 19) + ((size_t)(m0 + mi) << 9) + (n0 >> 1) + np];
        }
        __syncthreads();

        float4v S[4];
        #pragma unroll
        for (int nb = 0; nb < 4; nb++) {
            U4S8 bq0, bq1;
            bq0.u = *(uint4*)&sQu[nb*16 + l15][quad*4];
            bq1.u = *(uint4*)&sQu[nb*16 + l15][16 + quad*4];
            float4v zz = (float4v){0.f, 0.f, 0.f, 0.f};
            float4v p0 = __builtin_amdgcn_mfma_f32_16x16x32_bf16(kf0.s, bq0.s, zz, 0, 0, 0);
            S[nb] = __builtin_amdgcn_mfma_f32_16x16x32_bf16(kf1.s, bq1.s, p0, 0, 0, 0);
        }
        ushort* pRow[4];
        #pragma unroll
        for (int r = 0; r < 4; r++) pRow[r] = (ushort*)&sPu[w][quad*4 + r][0];
        #pragma unroll
        for (int r = 0; r < 4; r++) {
            int mi = w*16 + quad*4 + r;
            float sv[4];
            #pragma unroll
            for (int nb = 0; nb < 4; nb++) {
                int col = nb*16 + l15;
                uint lu = slwu[mi][col >> 1];
                float lv = (col & 1) ? __uint_as_float(lu & 0xFFFF0000u)
                                     : __uint_as_float(lu << 16);
                sv[nb] = S[nb][r] * 0.125f + lv;
            }
            float rm = fmaxf(fmaxf(sv[0], sv[1]), fmaxf(sv[2], sv[3]));
            #pragma unroll
            for (int off = 1; off < 16; off <<= 1)
                rm = fmaxf(rm, __shfl_xor(rm, off, 64));
            float newM = fmaxf(M[r], rm);
            float pr[4], rs = 0.f;
            #pragma unroll
            for (int nb = 0; nb < 4; nb++) {
                pr[nb] = __expf(sv[nb] - newM);
                rs += pr[nb];
            }
            #pragma unroll
            for (int off = 1; off < 16; off <<= 1)
                rs += __shfl_xor(rs, off, 64);
            float sc = __expf(M[r] - newM);
            M[r] = newM;
            Z[r] = Z[r] * sc + rs;
            #pragma unroll
            for (int kvb = 0; kvb < 4; kvb++) O[kvb][r] *= sc;
            #pragma unroll
            for (int nb = 0; nb < 4; nb++)
                pRow[r][nb*16 + l15] = f2bu(pr[nb]);
        }
        {
            U4S8 ap0, ap1;
            ap0.u = *(uint4*)&sPu[w][l15][quad*4];
            ap1.u = *(uint4*)&sPu[w][l15][16 + quad*4];
            #pragma unroll
            for (int kvb = 0; kvb < 4; kvb++) {
                U4S8 bv0, bv1;
                bv0.u = *(uint4*)&sVtu[kvb*16 + l15][quad*4];
                bv1.u = *(uint4*)&sVtu[kvb*16 + l15][16 + quad*4];
                O[kvb] = __builtin_amdgcn_mfma_f32_16x16x32_bf16(ap0.s, bv0.s, O[kvb], 0, 0, 0);
                O[kvb] = __builtin_amdgcn_mfma_f32_16x16x32_bf16(ap1.s, bv1.s, O[kvb], 0, 0, 0);
            }
        }
        __syncthreads();
    }

    ushort* ob = (ushort*)opartb;
    #pragma unroll
    for (int r = 0; r < 4; r++) {
        int m = m0 + w*16 + quad*4 + r;
        size_t row = ((size_t)ns * NH + h) * N + m;
        #pragma unroll
        for (int kvb = 0; kvb < 4; kvb++)
            ob[row * 64 + kvb*16 + l15] = f2bu(O[kvb][r]);
        if (l15 == 0) { mpart[row] = M[r]; zpart[row] = Z[r]; }
    }
}

// ---------------------------------------------------------------- k_final2 (merge + logit)
__global__ void __launch_bounds__(128) k_final2(
        const bf16* __restrict__ opartb, const float* __restrict__ mpart,
        const float* __restrict__ zpart, const int* __restrict__ order,
        const float* __restrict__ app, const float* __restrict__ lw,
        const float* __restrict__ lb, const float* __restrict__ sprob,
        float* __restrict__ out)
{
    __shared__ float sWgt[NH][NS];
    __shared__ float sInvZ[NH];
    __shared__ float red[2];
    int m = blockIdx.x, t = threadIdx.x;
    if (t < NH) {
        int h = t;
        float Ms[NS], Mg = -1e30f;
        #pragma unroll
        for (int ns = 0; ns < NS; ns++) {
            Ms[ns] = mpart[(size_t)ns * 16384 + h * 1024 + m];
            Mg = fmaxf(Mg, Ms[ns]);
        }
        float Zt = 0.f;
        #pragma unroll
        for (int ns = 0; ns < NS; ns++) {
            float wgt = __expf(Ms[ns] - Mg);
            sWgt[h][ns] = wgt;
            Zt += zpart[(size_t)ns * 16384 + h * 1024 + m] * wgt;
        }
        sInvZ[h] = 1.0f / Zt;
    }
    __syncthreads();
    int o = order[m];
    const ushort* ob = (const ushort*)opartb;
    float s = 0.f;
    for (int j = t; j < APP; j += 128) {
        int hh = j >> 6, kk = j & 63;
        size_t base = ((size_t)hh * 1024 + m) * 64 + kk;
        float val = 0.f;
        #pragma unroll
        for (int ns = 0; ns < NS; ns++)
            val += bu2f(ob[(size_t)ns * 1048576 + base]) * sWgt[hh][ns];
        float rv = val * sInvZ[hh] + app[o * APP + j];
        s += rv * lw[j];
    }
    #pragma unroll
    for (int off = 32; off > 0; off >>= 1) s += __shfl_down(s, off, 64);
    if ((t & 63) == 0) red[t >> 6] = s;
    __syncthreads();
    if (t == 0) {
        float tot = red[0] + red[1] + lb[0];
        float s1 = 1.0f / (1.0f + expf(-tot));
        out[m] = s1 * sprob[m];
    }
}

// ---------------------------------------------------------------- launch
extern "C" void kernel_launch(void* const* d_in, const int* in_sizes, int n_in,
                              void* d_out, int out_size, void* d_ws, size_t ws_size,
                              hipStream_t stream)
{
    const float* roi      = (const float*)d_in[0];
    const float* cls_loc  = (const float*)d_in[1];
    const float* score    = (const float*)d_in[2];
    const float* app      = (const float*)d_in[3];
    const int*   size     = (const int*)d_in[4];
    const float* rank_w   = (const float*)d_in[5];
    const float* rank_b   = (const float*)d_in[6];
    const float* feat_w   = (const float*)d_in[7];
    const float* feat_b   = (const float*)d_in[8];
    const float* logit_w  = (const float*)d_in[9];
    const float* logit_b  = (const float*)d_in[10];
    const float* wg_w     = (const float*)d_in[11];
    const float* wg_b     = (const float*)d_in[12];
    const float* wk_w     = (const float*)d_in[13];
    const float* wk_b     = (const float*)d_in[14];
    const float* wq_w     = (const float*)d_in[15];
    const float* wq_b     = (const float*)d_in[16];
    const float* wv_w     = (const float*)d_in[17];
    const float* wv_b     = (const float*)d_in[18];
    float* out = (float*)d_out;

    char* ws = (char*)d_ws;
    float* prob  = (float*)(ws + 0);
    int*   label = (int*)  (ws + 4096);
    float* bbox  = (float*)(ws + 8192);
    u64*   keys  = (u64*)  (ws + 24576);
    int*   order = (int*)  (ws + 32768);
    float* sprob = (float*)(ws + 36864);
    float* sbbox = (float*)(ws + 40960);
    bf16*  embb  = (bf16*) (ws + 57344);      // 256 KB
    bf16*  q     = (bf16*) (ws + 8970240);    // 2 MB
    bf16*  k     = (bf16*) (ws + 11067392);   // 2 MB
    bf16*  v     = (bf16*) (ws + 13164544);   // 2 MB
    bf16*  lwbuf = (bf16*) (ws + 17358848);   // 32 MB
    float* part  = (float*)(ws + 50913280);   // 4 MB   [8][1024][128] f32
    bf16*  opartb= (bf16*) (ws + 67690496);   // 4 MB   [NS][16384][64] bf16
    float* mpart = (float*)(ws + 84467712);   // 128 KB [NS][16384]
    float* zpart = (float*)(ws + 84729856);   // 128 KB

    k_prep<<<4, 256, 0, stream>>>(roi, cls_loc, score, size, prob, label, bbox, keys);
    k_rank<<<4, 256, 0, stream>>>(keys, prob, label, bbox, order, sprob, sbbox, out);
    k_geoemb<<<4224, 256, 0, stream>>>(order, app, feat_w, rank_w, part,
                                       sbbox, wg_w, wg_b, lwbuf);
    k_embsum<<<512, 256, 0, stream>>>(part, feat_b, rank_b, embb);
    k_qkv2<<<dim3(8, 16, 3), 256, 0, stream>>>(embb, wq_w, wq_b, wk_w, wk_b, wv_w, wv_b, q, k, v);
    k_attn4<<<dim3(16, 16, NS), 256, 0, stream>>>(q, k, v, lwbuf, opartb, mpart, zpart);
    k_final2<<<1024, 128, 0, stream>>>(opartb, mpart, zpart, order, app, logit_w, logit_b, sprob, out);
}